// Round 1
// baseline (1172.134 us; speedup 1.0000x reference)
//
#include <hip/hip_runtime.h>
#include <cstdint>
#include <math.h>

#define S 2048
#define D 64
#define NH 24                              /* B*H = 2*12 heads */
#define CTX_ELEMS ((size_t)NH * S * D)     /* context output elems */
#define SDP_SCALE 0.5f
#define MASK_FILL -1.0e9f
#define PBW 1032                           /* padded P-buffer row width (ushorts), 16B-aligned rows */

typedef __attribute__((ext_vector_type(8))) short   bf16x8;
typedef __attribute__((ext_vector_type(4))) float   f32x4;

__device__ __forceinline__ unsigned short f2bf(float x) {
    unsigned u = __builtin_bit_cast(unsigned, x);
    u += 0x7FFFu + ((u >> 16) & 1u);          // RNE
    return (unsigned short)(u >> 16);
}
__device__ __forceinline__ float bf2f(unsigned short b) {
    unsigned u = ((unsigned)b) << 16;
    return __builtin_bit_cast(float, u);
}

// ---------------- Fused single-pass SDPA -----------------------------------
// Block = 1024 thr (16 waves) owns 16 FULL Q-rows (all 2048 columns).
// Wave w computes QK^T col-tiles {w + 16*i, i<8}; raw fp32 scores stay in
// registers (32 VGPR). Exact 2-phase softmax via 2KB LDS cross-wave reduce.
// attn written to HBM exactly once; P (bf16) bounced through a 33KB LDS
// buffer in two 1024-col halves for the PV MFMA; 16 partial contexts reduced
// with LDS atomicAdd. Removes the 805 MB raw-score HBM round-trip.
// MFMA layouts (m89/m101-verified): A[m=lane&15][k=quad*8+j],
// B[k=quad*8+j][n=lane&15], C/D col=lane&15, row=quad*4+reg.
__global__ __launch_bounds__(1024, 4) void sdpa_fused(
    const float* __restrict__ q, const float* __restrict__ k,
    const float* __restrict__ v, const int* __restrict__ mask,
    float* __restrict__ out)
{
    const int t    = threadIdx.x;
    const int w    = t >> 6;                  // wave 0..15
    const int lane = t & 63;
    const int quad = lane >> 4, n = lane & 15;
    const int rbase = blockIdx.x * 16;        // 16 Q rows per block
    const int bh    = rbase >> 11;            // head index (2048 rows/head)

    __shared__ unsigned short pb[16 * PBW];   // bf16 P, one 1024-col half   (33.0 KB)
    __shared__ float mwS[16][16];             // per-wave row max            (1 KB)
    __shared__ float lwS[16][16];             // per-wave row sum            (1 KB)
    __shared__ float MS[16];                  // combined row max
    __shared__ float iLS[16];                 // combined 1/row-sum
    __shared__ float ctxred[16 * D];          // context reduction           (4 KB)

    ctxred[t] = 0.f;                          // 1024 thr == 16*64 elems

    // ---- Q fragments (16 rows shared by all waves; global reads are L1/L2 hits)
    bf16x8 qfh[2], qfl[2];
    #pragma unroll
    for (int ks = 0; ks < 2; ++ks) {
        const float* qp = q + (size_t)(rbase + n) * D + ks * 32 + quad * 8;
        float4 a = *(const float4*)qp;
        float4 b = *(const float4*)(qp + 4);
        float c[8] = {a.x, a.y, a.z, a.w, b.x, b.y, b.z, b.w};
        #pragma unroll
        for (int u = 0; u < 8; ++u) {
            unsigned short hb = f2bf(c[u]);
            qfh[ks][u] = (short)hb;
            qfl[ks][u] = (short)f2bf(c[u] - bf2f(hb));
        }
    }

    const float* khead = k + (size_t)bh * S * D;
    const float* vhead = v + (size_t)bh * S * D;

    // ---- QK^T: 8 tiles/wave, raw scores -> registers ----
    float s_reg[8][4];
    float m4[4] = {-INFINITY, -INFINITY, -INFINITY, -INFINITY};
    #pragma unroll
    for (int i = 0; i < 8; ++i) {
        const int tile = w + 16 * i;
        f32x4 c = {0.f, 0.f, 0.f, 0.f};
        #pragma unroll
        for (int ks = 0; ks < 2; ++ks) {
            const float* kp = khead + (size_t)(tile * 16 + n) * D + ks * 32 + quad * 8;
            float4 ka = *(const float4*)kp;
            float4 kb = *(const float4*)(kp + 4);
            float ce[8] = {ka.x, ka.y, ka.z, ka.w, kb.x, kb.y, kb.z, kb.w};
            bf16x8 bh_, bl_;
            #pragma unroll
            for (int u = 0; u < 8; ++u) {
                unsigned short hb = f2bf(ce[u]);
                bh_[u] = (short)hb;
                bl_[u] = (short)f2bf(ce[u] - bf2f(hb));
            }
            c = __builtin_amdgcn_mfma_f32_16x16x32_bf16(qfh[ks], bh_, c, 0, 0, 0);
            c = __builtin_amdgcn_mfma_f32_16x16x32_bf16(qfl[ks], bh_, c, 0, 0, 0);
            c = __builtin_amdgcn_mfma_f32_16x16x32_bf16(qfh[ks], bl_, c, 0, 0, 0);
        }
        const int colb = tile * 16 + n;
        #pragma unroll
        for (int r = 0; r < 4; ++r) {
            float sv = c[r] * SDP_SCALE;
            const int rowg = rbase + quad * 4 + r;
            if (mask[(size_t)rowg * S + colb] != 0) sv = MASK_FILL;
            s_reg[i][r] = sv;
            m4[r] = fmaxf(m4[r], sv);
        }
    }

    // ---- exact per-wave (m,l): reduce over the 16 column lanes ----
    #pragma unroll
    for (int r = 0; r < 4; ++r) {
        #pragma unroll
        for (int off = 1; off < 16; off <<= 1)
            m4[r] = fmaxf(m4[r], __shfl_xor(m4[r], off, 64));
    }
    float l4[4] = {0.f, 0.f, 0.f, 0.f};
    #pragma unroll
    for (int i = 0; i < 8; ++i) {
        #pragma unroll
        for (int r = 0; r < 4; ++r)
            l4[r] += __expf(s_reg[i][r] - m4[r]);
    }
    #pragma unroll
    for (int r = 0; r < 4; ++r) {
        #pragma unroll
        for (int off = 1; off < 16; off <<= 1)
            l4[r] += __shfl_xor(l4[r], off, 64);
    }
    if (n == 0) {
        #pragma unroll
        for (int r = 0; r < 4; ++r) {
            mwS[w][quad * 4 + r] = m4[r];
            lwS[w][quad * 4 + r] = l4[r];
        }
    }
    __syncthreads();

    // ---- combine across 16 waves (exact; all partials >= -1e9, never -inf)
    if (t < 16) {
        float M = -INFINITY;
        #pragma unroll
        for (int ww = 0; ww < 16; ++ww) M = fmaxf(M, mwS[ww][t]);
        float L = 0.f;
        #pragma unroll
        for (int ww = 0; ww < 16; ++ww) L += lwS[ww][t] * __expf(mwS[ww][t] - M);
        MS[t]  = M;
        iLS[t] = 1.0f / L;                    // L >= 1 always
    }
    __syncthreads();

    float* attn = out + CTX_ELEMS;
    f32x4 acc[4] = {{0.f,0.f,0.f,0.f},{0.f,0.f,0.f,0.f},
                    {0.f,0.f,0.f,0.f},{0.f,0.f,0.f,0.f}};

    // ---- two 1024-col halves: normalize->attn write (once) + P->LDS, then PV
    #pragma unroll
    for (int h = 0; h < 2; ++h) {
        #pragma unroll
        for (int ii = 0; ii < 4; ++ii) {
            const int i    = h * 4 + ii;
            const int tile = w + 16 * i;
            const int colb = tile * 16 + n;
            const int kloc = colb - h * 1024;            // in [0,1024)
            #pragma unroll
            for (int r = 0; r < 4; ++r) {
                const int row  = quad * 4 + r;
                const int rowg = rbase + row;
                float p = __expf(s_reg[i][r] - MS[row]) * iLS[row];
                attn[(size_t)rowg * S + colb] = p;        // final attn, written once
                pb[row * PBW + kloc] = f2bf(p);
            }
        }
        __syncthreads();

        // PV over this half: wave w handles k in [w*64, w*64+64)
        #pragma unroll
        for (int ks = 0; ks < 2; ++ks) {
            const int kloc0 = w * 64 + ks * 32 + quad * 8;
            bf16x8 af = *(const bf16x8*)&pb[n * PBW + kloc0];   // A[m=n][k]
            const int kg = h * 1024 + kloc0;
            #pragma unroll
            for (int dt = 0; dt < 4; ++dt) {
                const float* vp = vhead + (size_t)kg * D + dt * 16 + n;
                bf16x8 vb;
                #pragma unroll
                for (int j = 0; j < 8; ++j) vb[j] = (short)f2bf(vp[(size_t)j * D]);
                acc[dt] = __builtin_amdgcn_mfma_f32_16x16x32_bf16(af, vb, acc[dt], 0, 0, 0);
            }
        }
        __syncthreads();
    }

    // ---- reduce the 16 per-wave partial contexts ----
    #pragma unroll
    for (int dt = 0; dt < 4; ++dt) {
        #pragma unroll
        for (int r = 0; r < 4; ++r)
            atomicAdd(&ctxred[(quad * 4 + r) * D + dt * 16 + n], acc[dt][r]);
    }
    __syncthreads();

    // coalesced context write: thread t -> (row t/64, col t%64)
    out[(size_t)(rbase + (t >> 6)) * D + (t & 63)] = ctxred[t];
}

extern "C" void kernel_launch(void* const* d_in, const int* in_sizes, int n_in,
                              void* d_out, int out_size, void* d_ws, size_t ws_size,
                              hipStream_t stream) {
    const float* q    = (const float*)d_in[0];
    const float* k    = (const float*)d_in[1];
    const float* v    = (const float*)d_in[2];
    const int*   mask = (const int*)d_in[3];
    float* out = (float*)d_out;

    sdpa_fused<<<NH * S / 16, 1024, 0, stream>>>(q, k, v, mask, out);
}

// Round 2
// 1136.666 us; speedup vs baseline: 1.0312x; 1.0312x over previous
//
#include <hip/hip_runtime.h>
#include <cstdint>
#include <math.h>

#define S 2048
#define D 64
#define NH 24                              /* B*H = 2*12 heads */
#define CTX_ELEMS ((size_t)NH * S * D)     /* context output elems */
#define SDP_SCALE 0.5f
#define MASK_FILL -1.0e9f

#define PQW 260      /* fp32 P chunk row stride (floats): 256 + 4 pad */
#define VQW 76       /* bf16 V chunk row stride (shorts): 64 + 12 pad, 8B-aligned rows */

typedef __attribute__((ext_vector_type(8))) short   bf16x8;
typedef __attribute__((ext_vector_type(4))) float   f32x4;
typedef __attribute__((ext_vector_type(4))) unsigned short us4;

__device__ __forceinline__ unsigned short f2bf(float x) {
    unsigned u = __builtin_bit_cast(unsigned, x);
    u += 0x7FFFu + ((u >> 16) & 1u);          // RNE
    return (unsigned short)(u >> 16);
}
__device__ __forceinline__ float bf2f(unsigned short b) {
    unsigned u = ((unsigned)b) << 16;
    return __builtin_bit_cast(float, u);
}

// ---------------- Fused single-pass SDPA, vectorized streams ---------------
// Block = 1024 thr (16 waves) owns 16 FULL Q-rows (all 2048 columns).
// All HBM streams are >=16B/lane:
//   mask: 8 int4/thread -> LDS bytes (32 KB, QK phase reads LDS)
//   attn: fp32 P chunk in LDS -> 1 float4/thread/chunk (1KB/wave/instr)
//   V:    staged per 256-row chunk as bf16 in LDS via coalesced float4
// Raw fp32 scores live in registers (32 VGPR); exact 2-phase softmax.
// PV per chunk: wave w -> k-slice (w&7), dt-pair (w>>3); LDS atomicAdd combine.
// MFMA layouts (m89/m101-verified): A[m=lane&15][k=quad*8+j],
// B[k=quad*8+j][n=lane&15], C/D col=lane&15, row=quad*4+reg.
__global__ __launch_bounds__(1024, 4) void sdpa_fused(
    const float* __restrict__ q, const float* __restrict__ k,
    const float* __restrict__ v, const int* __restrict__ mask,
    float* __restrict__ out)
{
    const int t    = threadIdx.x;
    const int w    = t >> 6;                  // wave 0..15
    const int lane = t & 63;
    const int quad = lane >> 4, n = lane & 15;
    const int rbase = blockIdx.x * 16;        // 16 Q rows per block
    const int bh    = rbase >> 11;            // head index (2048 rows/head)

    // phase-disjoint LDS union: [mask bytes 32KB] vs [pq 16.6KB | vq 38.9KB]
    __shared__ __align__(16) char pool[16640 + 38912];
    unsigned char* maskS = (unsigned char*)pool;               // 16 x 2048 B
    float*          pq   = (float*)pool;                       // 16 x PQW f32
    unsigned short* vq   = (unsigned short*)(pool + 16640);    // 256 x VQW bf16

    __shared__ float mwS[16][16];             // per-wave row max
    __shared__ float lwS[16][16];             // per-wave row sum
    __shared__ float MS[16];                  // combined row max
    __shared__ float iLS[16];                 // combined 1/row-sum
    __shared__ float ctxred[16 * D];          // context reduction (4 KB)

    ctxred[t] = 0.f;

    // ---- stage mask: 16 rows x 2048 int32 -> bytes, 8 coalesced int4/thread
    {
        const int4* m4p = (const int4*)(mask + (size_t)rbase * S);
        #pragma unroll
        for (int u = 0; u < 8; ++u) {
            const int idx = u * 1024 + t;          // int4 index, row=idx>>9
            int4 mv = m4p[idx];
            uchar4 mb;
            mb.x = (unsigned char)(mv.x != 0);
            mb.y = (unsigned char)(mv.y != 0);
            mb.z = (unsigned char)(mv.z != 0);
            mb.w = (unsigned char)(mv.w != 0);
            *(uchar4*)&maskS[idx * 4] = mb;
        }
    }

    // ---- Q fragments (16 rows shared by all waves; L1/L2 hits) ----
    bf16x8 qfh[2], qfl[2];
    #pragma unroll
    for (int ks = 0; ks < 2; ++ks) {
        const float* qp = q + (size_t)(rbase + n) * D + ks * 32 + quad * 8;
        float4 a = *(const float4*)qp;
        float4 b = *(const float4*)(qp + 4);
        float c[8] = {a.x, a.y, a.z, a.w, b.x, b.y, b.z, b.w};
        #pragma unroll
        for (int u = 0; u < 8; ++u) {
            unsigned short hb = f2bf(c[u]);
            qfh[ks][u] = (short)hb;
            qfl[ks][u] = (short)f2bf(c[u] - bf2f(hb));
        }
    }
    __syncthreads();                           // maskS visible

    const float* khead = k + (size_t)bh * S * D;
    const float* vhead = v + (size_t)bh * S * D;

    // ---- QK^T: 8 tiles/wave, raw scores -> registers ----
    float s_reg[8][4];
    float m4[4] = {-INFINITY, -INFINITY, -INFINITY, -INFINITY};
    #pragma unroll
    for (int i = 0; i < 8; ++i) {
        const int tile = w + 16 * i;
        f32x4 c = {0.f, 0.f, 0.f, 0.f};
        #pragma unroll
        for (int ks = 0; ks < 2; ++ks) {
            const float* kp = khead + (size_t)(tile * 16 + n) * D + ks * 32 + quad * 8;
            float4 ka = *(const float4*)kp;
            float4 kb = *(const float4*)(kp + 4);
            float ce[8] = {ka.x, ka.y, ka.z, ka.w, kb.x, kb.y, kb.z, kb.w};
            bf16x8 bh_, bl_;
            #pragma unroll
            for (int u = 0; u < 8; ++u) {
                unsigned short hb = f2bf(ce[u]);
                bh_[u] = (short)hb;
                bl_[u] = (short)f2bf(ce[u] - bf2f(hb));
            }
            c = __builtin_amdgcn_mfma_f32_16x16x32_bf16(qfh[ks], bh_, c, 0, 0, 0);
            c = __builtin_amdgcn_mfma_f32_16x16x32_bf16(qfl[ks], bh_, c, 0, 0, 0);
            c = __builtin_amdgcn_mfma_f32_16x16x32_bf16(qfh[ks], bl_, c, 0, 0, 0);
        }
        #pragma unroll
        for (int r = 0; r < 4; ++r) {
            float sv = c[r] * SDP_SCALE;
            if (maskS[(quad * 4 + r) * 2048 + tile * 16 + n]) sv = MASK_FILL;
            s_reg[i][r] = sv;
            m4[r] = fmaxf(m4[r], sv);
        }
    }

    // ---- per-wave exact (m,l); cache e = exp(s - m_wave) in s_reg ----
    #pragma unroll
    for (int r = 0; r < 4; ++r) {
        #pragma unroll
        for (int off = 1; off < 16; off <<= 1)
            m4[r] = fmaxf(m4[r], __shfl_xor(m4[r], off, 64));
    }
    float l4[4] = {0.f, 0.f, 0.f, 0.f};
    #pragma unroll
    for (int i = 0; i < 8; ++i) {
        #pragma unroll
        for (int r = 0; r < 4; ++r) {
            float e = __expf(s_reg[i][r] - m4[r]);
            s_reg[i][r] = e;
            l4[r] += e;
        }
    }
    #pragma unroll
    for (int r = 0; r < 4; ++r) {
        #pragma unroll
        for (int off = 1; off < 16; off <<= 1)
            l4[r] += __shfl_xor(l4[r], off, 64);
    }
    if (n == 0) {
        #pragma unroll
        for (int r = 0; r < 4; ++r) {
            mwS[w][quad * 4 + r] = m4[r];
            lwS[w][quad * 4 + r] = l4[r];
        }
    }
    __syncthreads();

    // ---- combine across 16 waves (exact) ----
    if (t < 16) {
        float M = -INFINITY;
        #pragma unroll
        for (int ww = 0; ww < 16; ++ww) M = fmaxf(M, mwS[ww][t]);
        float L = 0.f;
        #pragma unroll
        for (int ww = 0; ww < 16; ++ww) L += lwS[ww][t] * __expf(mwS[ww][t] - M);
        MS[t]  = M;
        iLS[t] = 1.0f / L;                    // L >= 1 always
    }
    __syncthreads();                          // also: all maskS reads done (pool reuse)

    // per-row fold factor: p = e * exp(m_wave - M) / L
    float f4[4];
    #pragma unroll
    for (int r = 0; r < 4; ++r)
        f4[r] = __expf(m4[r] - MS[quad * 4 + r]) * iLS[quad * 4 + r];

    float* attn = out + CTX_ELEMS;
    const int s_sl = w & 7;                   // k-slice (32 k) within chunk
    const int dt0  = (w >> 3) * 2;            // this wave's d-tile pair
    f32x4 acc2[2] = {{0.f,0.f,0.f,0.f},{0.f,0.f,0.f,0.f}};

    // ---- 8 chunks of 256 columns: stage V+P, write attn, PV MFMA ----
    #pragma unroll
    for (int ch = 0; ch < 8; ++ch) {
        // stage V chunk: 256 k-rows x 64 d, coalesced float4 -> bf16 LDS
        {
            const float4* v4 = (const float4*)(vhead + (size_t)ch * 256 * D);
            #pragma unroll
            for (int u = 0; u < 4; ++u) {
                const int idx = u * 1024 + t;
                const int kloc = idx >> 4, d0 = (idx & 15) * 4;
                float4 vv = v4[idx];
                us4 vb = { f2bf(vv.x), f2bf(vv.y), f2bf(vv.z), f2bf(vv.w) };
                *(us4*)&vq[kloc * VQW + d0] = vb;
            }
        }
        // stage P chunk (tile i == ch): fp32, exact normalized values
        #pragma unroll
        for (int r = 0; r < 4; ++r)
            pq[(quad * 4 + r) * PQW + w * 16 + n] = s_reg[ch][r] * f4[r];
        __syncthreads();

        // attn write: 1 float4/thread, wave = one contiguous 1KB row segment
        {
            const int row = t >> 6, c4 = (t & 63) * 4;
            float4 pv = *(const float4*)&pq[row * PQW + c4];
            *(float4*)(attn + (size_t)(rbase + row) * S + ch * 256 + c4) = pv;
        }

        // A-frag: P[m=n][k = s_sl*32 + quad*8 + j]
        bf16x8 af;
        {
            const float* ap = &pq[n * PQW + s_sl * 32 + quad * 8];
            float4 a0 = *(const float4*)ap;
            float4 a1 = *(const float4*)(ap + 4);
            af[0] = (short)f2bf(a0.x); af[1] = (short)f2bf(a0.y);
            af[2] = (short)f2bf(a0.z); af[3] = (short)f2bf(a0.w);
            af[4] = (short)f2bf(a1.x); af[5] = (short)f2bf(a1.y);
            af[6] = (short)f2bf(a1.z); af[7] = (short)f2bf(a1.w);
        }
        // B-frags from vq (2-way-conflict-free u16 reads) + MFMA
        #pragma unroll
        for (int di = 0; di < 2; ++di) {
            const int dt = dt0 + di;
            bf16x8 vb;
            #pragma unroll
            for (int j = 0; j < 8; ++j)
                vb[j] = (short)vq[(s_sl * 32 + quad * 8 + j) * VQW + dt * 16 + n];
            acc2[di] = __builtin_amdgcn_mfma_f32_16x16x32_bf16(af, vb, acc2[di], 0, 0, 0);
        }
        __syncthreads();                       // before next chunk overwrites pq/vq
    }

    // ---- combine 16 per-wave partial contexts ----
    #pragma unroll
    for (int di = 0; di < 2; ++di) {
        #pragma unroll
        for (int r = 0; r < 4; ++r)
            atomicAdd(&ctxred[(quad * 4 + r) * D + (dt0 + di) * 16 + n], acc2[di][r]);
    }
    __syncthreads();

    // coalesced context write: thread t -> (row t/64, col t%64)
    out[(size_t)(rbase + (t >> 6)) * D + (t & 63)] = ctxred[t];
}

extern "C" void kernel_launch(void* const* d_in, const int* in_sizes, int n_in,
                              void* d_out, int out_size, void* d_ws, size_t ws_size,
                              hipStream_t stream) {
    const float* q    = (const float*)d_in[0];
    const float* k    = (const float*)d_in[1];
    const float* v    = (const float*)d_in[2];
    const int*   mask = (const int*)d_in[3];
    float* out = (float*)d_out;

    sdpa_fused<<<NH * S / 16, 1024, 0, stream>>>(q, k, v, mask, out);
}

// Round 3
// 939.057 us; speedup vs baseline: 1.2482x; 1.2104x over previous
//
#include <hip/hip_runtime.h>
#include <cstdint>
#include <math.h>

#define S 2048
#define D 64
#define NH 24                              /* B*H = 2*12 heads */
#define CTX_ELEMS ((size_t)NH * S * D)     /* context output elems */
#define SDP_SCALE 0.5f
#define MASK_FILL -1.0e9f
#define PQW 260                            /* fp32 P row stride (floats) */
#define KE  ((size_t)NH * S * D)           /* elems per bf16 tensor (3.145M) */

typedef __attribute__((ext_vector_type(8))) short          bf16x8;
typedef __attribute__((ext_vector_type(4))) float          f32x4;
typedef __attribute__((ext_vector_type(8))) unsigned short us8;

__device__ __forceinline__ unsigned short f2bf(float x) {
    unsigned u = __builtin_bit_cast(unsigned, x);
    u += 0x7FFFu + ((u >> 16) & 1u);          // RNE
    return (unsigned short)(u >> 16);
}
__device__ __forceinline__ float bf2f(unsigned short b) {
    unsigned u = ((unsigned)b) << 16;
    return __builtin_bit_cast(float, u);
}

// ---------------- Preprocess: K -> split-bf16 frags, V -> bf16 frags -------
// ws layout (shorts): khi [0,KE) | klo [KE,2KE) | vfr [2KE,3KE)  = 18.9 MB.
// K frag: khi[(((bh*128+tile)*2+ks)*64+lane)*8 + j] = hi(K[tile*16+n][ks*32+quad*8+j])
// V frag: vfr[((((bh*8+ch)*8+sl)*4+dt)*64+lane)*8 + j] = bf16(V[ch*256+sl*32+quad*8+j][dt*16+n])
// Main-kernel fragment loads become lane-contiguous dwordx4 (1 KB/wave/instr).
__global__ __launch_bounds__(256) void sdpa_preproc(
    const float* __restrict__ k, const float* __restrict__ v,
    unsigned short* __restrict__ ws)
{
    const int g = blockIdx.x * 256 + threadIdx.x;     // 0 .. 786431
    unsigned short* khi = ws;
    unsigned short* klo = ws + KE;
    unsigned short* vfr = ws + 2 * KE;

    if (g < 393216) {
        // ---- K fragments (split hi/lo) ----
        const int lane = g & 63, n = lane & 15, quad = lane >> 4;
        const int ks   = (g >> 6) & 1;
        const int tile = (g >> 7) & 127;
        const int bh   = g >> 14;
        const float* kp = k + (size_t)bh * S * D + (size_t)(tile * 16 + n) * D
                            + ks * 32 + quad * 8;
        float4 a = *(const float4*)kp;
        float4 b = *(const float4*)(kp + 4);
        float c[8] = {a.x, a.y, a.z, a.w, b.x, b.y, b.z, b.w};
        us8 h, l;
        #pragma unroll
        for (int u = 0; u < 8; ++u) {
            unsigned short hb = f2bf(c[u]);
            h[u] = hb;
            l[u] = f2bf(c[u] - bf2f(hb));
        }
        *(us8*)(khi + (size_t)g * 8) = h;
        *(us8*)(klo + (size_t)g * 8) = l;
    } else {
        // ---- V fragments (plain bf16) ----
        const int g2 = g - 393216;
        const int lane = g2 & 63, n = lane & 15, quad = lane >> 4;
        const int dt = (g2 >> 6) & 3;
        const int sl = (g2 >> 8) & 7;
        const int ch = (g2 >> 11) & 7;
        const int bh = g2 >> 14;
        const float* vp = v + (size_t)bh * S * D
                            + (size_t)(ch * 256 + sl * 32 + quad * 8) * D
                            + dt * 16 + n;
        us8 o;
        #pragma unroll
        for (int j = 0; j < 8; ++j) o[j] = f2bf(vp[(size_t)j * D]);
        *(us8*)(vfr + (size_t)g2 * 8) = o;
    }
}

// ---------------- Fused single-pass SDPA, frag-ready operands --------------
// Block = 1024 thr (16 waves) owns 16 FULL Q-rows. Raw e=exp(s-m_w) in regs.
// K/V fragments load directly from ws (coalesced 16B/lane, L2-resident).
// Only LDS: mask bytes (phase 1) unioned with double-buffered fp32 P tile.
// MFMA layouts (m89/m101-verified): A[m=lane&15][k=quad*8+j],
// B[k=quad*8+j][n=lane&15], C/D col=lane&15, row=quad*4+reg.
__global__ __launch_bounds__(1024, 4) void sdpa_fused(
    const float* __restrict__ q, const int* __restrict__ mask,
    const unsigned short* __restrict__ ws, float* __restrict__ out)
{
    const int t    = threadIdx.x;
    const int w    = t >> 6;                  // wave 0..15
    const int lane = t & 63;
    const int quad = lane >> 4, n = lane & 15;
    const int rbase = blockIdx.x * 16;        // 16 Q rows per block
    const int bh    = rbase >> 11;            // head index

    const unsigned short* khi = ws;
    const unsigned short* klo = ws + KE;
    const unsigned short* vfr = ws + 2 * KE;

    // phase union: [mask bytes 32KB] then [pq double buffer 2x16x260 f32 = 33.3KB]
    __shared__ __align__(16) char pool[2 * 16 * PQW * 4];
    unsigned char* maskS = (unsigned char*)pool;
    float*         pq    = (float*)pool;

    __shared__ float mwS[16][16];
    __shared__ float lwS[16][16];
    __shared__ float MS[16];
    __shared__ float iLS[16];
    __shared__ float ctxred[16 * D];

    ctxred[t] = 0.f;

    // ---- stage mask: 16 rows x 2048 int32 -> bytes, 8 coalesced int4/thread
    {
        const int4* m4p = (const int4*)(mask + (size_t)rbase * S);
        #pragma unroll
        for (int u = 0; u < 8; ++u) {
            const int idx = u * 1024 + t;
            int4 mv = m4p[idx];
            uchar4 mb;
            mb.x = (unsigned char)(mv.x != 0);
            mb.y = (unsigned char)(mv.y != 0);
            mb.z = (unsigned char)(mv.z != 0);
            mb.w = (unsigned char)(mv.w != 0);
            *(uchar4*)&maskS[idx * 4] = mb;
        }
    }

    // ---- Q fragments: split in-kernel (16 rows only, L2 hits) ----
    bf16x8 qfh[2], qfl[2];
    #pragma unroll
    for (int ks = 0; ks < 2; ++ks) {
        const float* qp = q + (size_t)(rbase + n) * D + ks * 32 + quad * 8;
        float4 a = *(const float4*)qp;
        float4 b = *(const float4*)(qp + 4);
        float c[8] = {a.x, a.y, a.z, a.w, b.x, b.y, b.z, b.w};
        #pragma unroll
        for (int u = 0; u < 8; ++u) {
            unsigned short hb = f2bf(c[u]);
            qfh[ks][u] = (short)hb;
            qfl[ks][u] = (short)f2bf(c[u] - bf2f(hb));
        }
    }
    __syncthreads();                           // maskS visible

    // ---- QK^T: 8 tiles/wave, frag-ready K, scores -> registers ----
    float s_reg[8][4];
    float m4[4] = {-INFINITY, -INFINITY, -INFINITY, -INFINITY};
    #pragma unroll
    for (int i = 0; i < 8; ++i) {
        const int tile = w + 16 * i;
        const size_t kb = ((((size_t)bh * 128 + tile) * 2) * 64 + lane) * 8;
        bf16x8 kh0 = *(const bf16x8*)(khi + kb);
        bf16x8 kl0 = *(const bf16x8*)(klo + kb);
        bf16x8 kh1 = *(const bf16x8*)(khi + kb + 512);   // ks=1: +64 lanes*8
        bf16x8 kl1 = *(const bf16x8*)(klo + kb + 512);
        f32x4 c = {0.f, 0.f, 0.f, 0.f};
        c = __builtin_amdgcn_mfma_f32_16x16x32_bf16(qfh[0], kh0, c, 0, 0, 0);
        c = __builtin_amdgcn_mfma_f32_16x16x32_bf16(qfl[0], kh0, c, 0, 0, 0);
        c = __builtin_amdgcn_mfma_f32_16x16x32_bf16(qfh[0], kl0, c, 0, 0, 0);
        c = __builtin_amdgcn_mfma_f32_16x16x32_bf16(qfh[1], kh1, c, 0, 0, 0);
        c = __builtin_amdgcn_mfma_f32_16x16x32_bf16(qfl[1], kh1, c, 0, 0, 0);
        c = __builtin_amdgcn_mfma_f32_16x16x32_bf16(qfh[1], kl1, c, 0, 0, 0);
        #pragma unroll
        for (int r = 0; r < 4; ++r) {
            float sv = c[r] * SDP_SCALE;
            if (maskS[(quad * 4 + r) * 2048 + tile * 16 + n]) sv = MASK_FILL;
            s_reg[i][r] = sv;
            m4[r] = fmaxf(m4[r], sv);
        }
    }

    // ---- per-wave exact (m,l); cache e = exp(s - m_wave) in s_reg ----
    #pragma unroll
    for (int r = 0; r < 4; ++r) {
        #pragma unroll
        for (int off = 1; off < 16; off <<= 1)
            m4[r] = fmaxf(m4[r], __shfl_xor(m4[r], off, 64));
    }
    float l4[4] = {0.f, 0.f, 0.f, 0.f};
    #pragma unroll
    for (int i = 0; i < 8; ++i) {
        #pragma unroll
        for (int r = 0; r < 4; ++r) {
            float e = __expf(s_reg[i][r] - m4[r]);
            s_reg[i][r] = e;
            l4[r] += e;
        }
    }
    #pragma unroll
    for (int r = 0; r < 4; ++r) {
        #pragma unroll
        for (int off = 1; off < 16; off <<= 1)
            l4[r] += __shfl_xor(l4[r], off, 64);
    }
    if (n == 0) {
        #pragma unroll
        for (int r = 0; r < 4; ++r) {
            mwS[w][quad * 4 + r] = m4[r];
            lwS[w][quad * 4 + r] = l4[r];
        }
    }
    __syncthreads();

    if (t < 16) {
        float M = -INFINITY;
        #pragma unroll
        for (int ww = 0; ww < 16; ++ww) M = fmaxf(M, mwS[ww][t]);
        float L = 0.f;
        #pragma unroll
        for (int ww = 0; ww < 16; ++ww) L += lwS[ww][t] * __expf(mwS[ww][t] - M);
        MS[t]  = M;
        iLS[t] = 1.0f / L;                    // L >= 1 always
    }
    __syncthreads();                          // also: last maskS read done (pool reuse)

    float f4[4];
    #pragma unroll
    for (int r = 0; r < 4; ++r)
        f4[r] = __expf(m4[r] - MS[quad * 4 + r]) * iLS[quad * 4 + r];

    float* attn = out + CTX_ELEMS;
    const int s_sl = w & 7;                   // 32-k slice within chunk
    const int dt0  = (w >> 3) * 2;            // this wave's d-tile pair
    f32x4 acc2[2] = {{0.f,0.f,0.f,0.f},{0.f,0.f,0.f,0.f}};

    // prologue: stage P chunk 0 into buf 0
    #pragma unroll
    for (int r = 0; r < 4; ++r)
        pq[(quad * 4 + r) * PQW + w * 16 + n] = s_reg[0][r] * f4[r];

    // ---- 8 chunks of 256 columns, double-buffered P ----
    #pragma unroll
    for (int ch = 0; ch < 8; ++ch) {
        __syncthreads();                       // P(ch) visible; old consumers done
        float* pb = pq + (ch & 1) * 16 * PQW;

        // attn write: 1 float4/thread, wave = contiguous 1KB row segment
        {
            const int row = t >> 6, c4 = (t & 63) * 4;
            float4 pv = *(const float4*)&pb[row * PQW + c4];
            *(float4*)(attn + (size_t)(rbase + row) * S + ch * 256 + c4) = pv;
        }

        // A-frag: P[m=n][k = s_sl*32 + quad*8 + j]
        bf16x8 af;
        {
            const float* ap = &pb[n * PQW + s_sl * 32 + quad * 8];
            float4 a0 = *(const float4*)ap;
            float4 a1 = *(const float4*)(ap + 4);
            af[0] = (short)f2bf(a0.x); af[1] = (short)f2bf(a0.y);
            af[2] = (short)f2bf(a0.z); af[3] = (short)f2bf(a0.w);
            af[4] = (short)f2bf(a1.x); af[5] = (short)f2bf(a1.y);
            af[6] = (short)f2bf(a1.z); af[7] = (short)f2bf(a1.w);
        }

        // B-frags: direct coalesced 16B loads from frag-ready V
        #pragma unroll
        for (int di = 0; di < 2; ++di) {
            const size_t vb_off =
                (((((size_t)bh * 8 + ch) * 8 + s_sl) * 4 + (dt0 + di)) * 64 + lane) * 8;
            bf16x8 vb = *(const bf16x8*)(vfr + vb_off);
            acc2[di] = __builtin_amdgcn_mfma_f32_16x16x32_bf16(af, vb, acc2[di], 0, 0, 0);
        }

        // stage next P chunk into the other buffer (consumed two syncs ago)
        if (ch < 7) {
            float* pn = pq + ((ch + 1) & 1) * 16 * PQW;
            #pragma unroll
            for (int r = 0; r < 4; ++r)
                pn[(quad * 4 + r) * PQW + w * 16 + n] = s_reg[ch + 1][r] * f4[r];
        }
    }
    __syncthreads();

    // ---- combine 16 per-wave partial contexts ----
    #pragma unroll
    for (int di = 0; di < 2; ++di) {
        #pragma unroll
        for (int r = 0; r < 4; ++r)
            atomicAdd(&ctxred[(quad * 4 + r) * D + (dt0 + di) * 16 + n], acc2[di][r]);
    }
    __syncthreads();

    out[(size_t)(rbase + (t >> 6)) * D + (t & 63)] = ctxred[t];
}

extern "C" void kernel_launch(void* const* d_in, const int* in_sizes, int n_in,
                              void* d_out, int out_size, void* d_ws, size_t ws_size,
                              hipStream_t stream) {
    const float* q    = (const float*)d_in[0];
    const float* k    = (const float*)d_in[1];
    const float* v    = (const float*)d_in[2];
    const int*   mask = (const int*)d_in[3];
    float* out = (float*)d_out;
    unsigned short* ws = (unsigned short*)d_ws;

    sdpa_preproc<<<3072, 256, 0, stream>>>(k, v, ws);
    sdpa_fused<<<NH * S / 16, 1024, 0, stream>>>(q, mask, ws, out);
}